// Round 5
// baseline (1008.808 us; speedup 1.0000x reference)
//
#include <hip/hip_runtime.h>
#include <float.h>

// VQ-VAE vector quantizer, MI355X fp32 vector-ALU version, round 6
// (third submission; rounds 3-4 were infra failures — container died during
// acquire both times, kernel never measured; source is audit-clean for
// hang/OOB/barrier-divergence container-killer classes).
// z: [32,64,32,32] f32, codebook: [1024,64] f32
// out (f32 flat): z_q [2097152] | loss [1] | indices-as-float [32768]
//
// Numerics contract (DO NOT CHANGE — bitwise-matches the numpy fp32 ref):
//  - code/pixel norms: numpy pairwise-sum tree over 64 rounded squares,
//    fp contract OFF (streamed in 8-element chunks, identical order/grouping)
//  - dot: single c-ascending fma chain per (pixel, code)
//  - score: fl(fl(zz+ee) - 2*dot), first-min selection (strict <, ascending k
//    at every merge level), wave w owns codes [w*128, w*128+128)
//
// Round-6 perf change: rounds 2-5 all hit the same wall — any layout with
// >128 codebook floats or >64 z floats of per-lane/SGPR state loses to the
// allocator (r4 spill, r5 SGPR-overflow -> per-lane codebook loads = 14x
// VALU bloat). Inverted placement: LANE = CODE. Each lane keeps ITS OWN
// 64-float codebook row in VGPRs (16 contiguous dwordx4, per-lane, zero
// SGPR pressure); the 64 pixel vectors sit in LDS and are broadcast via
// wave-uniform ds_read_b128 (conflict-free). Per-lane state ~105 regs by
// construction -> launch_bounds(512,4) honored -> 2 blocks/CU, 16 waves/CU.
// Scores (one-code-per-lane) go through a pad-17 per-wave LDS buffer
// (17 coprime 32 -> conflict-free write & read), then a 16-code scan per
// lane + 2-step shfl_xor lex-(v,i) merge preserves exact first-min.

#define DIM       64
#define N_EMB     1024
#define LOSS_OFF  2097152
#define IDX_OFF   2097153
// loss = 1.25 * sum / 2^21  (exact fp32 constant)
#define LOSS_SCALE 5.9604644775390625e-07f

// grid 512 blocks x 512 threads; block = 64 pixels, 8 waves;
// wave w owns codes [w*128, w*128+128) as two 64-code tiles, lane = code.
__global__ __launch_bounds__(512, 4)
void vq_main(const float* __restrict__ z, const float* __restrict__ cb,
             float* __restrict__ out, float* __restrict__ ws_partial) {
    __shared__ float  esq[N_EMB];        // 4 KB   code norms
    __shared__ float4 vzT[64 * 16];      // 16 KB  pixel vectors, swizzled f4 slots
    __shared__ float  zzs[64];           //        pixel norms
    __shared__ float  sbuf[8][64 * 17];  // 34 KB  per-wave score buf, pad-17
    __shared__ float  cand_val[8 * 64];  // 2 KB
    __shared__ int    cand_idx[8 * 64];  // 2 KB
    __shared__ int    fidx[64];
    __shared__ float  lred[8];

    const int tid  = threadIdx.x;
    const int lane = tid & 63;
    const int wave = __builtin_amdgcn_readfirstlane(tid >> 6);  // uniform
    const int n0   = blockIdx.x * 64;          // first pixel of this block
    const int b    = n0 >> 10;                 // batch image (1024 px each)
    const int hw0  = n0 & 1023;
    const size_t zbase = (size_t)b * 65536 + (size_t)hw0;  // z[b][c][hw]

    // ---- 1) codebook squared norms -> LDS (2 codes/thread) ----
    // Streamed 8-at-a-time; element order & pairwise tree identical to
    // numpy pairwise_sum: r[j] = sum_m a[j+8m]^2 ascending m, then pairwise.
    {
        #pragma clang fp contract(off)
        for (int t = 0; t < 2; ++t) {
            const int k = tid * 2 + t;
            const float4* row = (const float4*)(cb + (size_t)k * DIM);
            float r[8];
            #pragma unroll
            for (int m = 0; m < 8; ++m) {
                const float4 x0 = row[2 * m];
                const float4 x1 = row[2 * m + 1];
                const float a[8] = {x0.x, x0.y, x0.z, x0.w,
                                    x1.x, x1.y, x1.z, x1.w};
                #pragma unroll
                for (int j = 0; j < 8; ++j) {
                    const float p = a[j] * a[j];
                    if (m == 0) r[j] = p; else r[j] = r[j] + p;
                }
            }
            esq[k] = ((r[0] + r[1]) + (r[2] + r[3]))
                   + ((r[4] + r[5]) + (r[6] + r[7]));
        }
    }

    // ---- 2) stage 64 pixel vectors -> LDS (all 512 threads, coalesced) ----
    // thread (px=lane, c-octet=wave). float4 slot s of pixel p stored at
    // vzT[p*16 + (s ^ (p&15))]; slot s holds channels 4s..4s+3 verbatim.
    // Swizzle kills the write-side conflict (64 lanes, row stride 256 B).
    {
        const int px = lane;
        const int c0 = wave * 8;
        float a[8];
        #pragma unroll
        for (int j = 0; j < 8; ++j)
            a[j] = z[zbase + (size_t)(c0 + j) * 1024 + px];      // coalesced
        const int sw = px & 15;
        vzT[px * 16 + ((wave * 2)     ^ sw)] = make_float4(a[0], a[1], a[2], a[3]);
        vzT[px * 16 + ((wave * 2 + 1) ^ sw)] = make_float4(a[4], a[5], a[6], a[7]);
    }
    // ---- 3) wave 0: pixel norms (numpy tree, from global, L1/L2-hot) ----
    if (wave == 0) {
        #pragma clang fp contract(off)
        float r[8];
        #pragma unroll
        for (int m = 0; m < 8; ++m) {
            float a[8];
            #pragma unroll
            for (int j = 0; j < 8; ++j)
                a[j] = z[zbase + (size_t)(8 * m + j) * 1024 + lane]; // coalesced
            #pragma unroll
            for (int j = 0; j < 8; ++j) {
                const float p = a[j] * a[j];
                if (m == 0) r[j] = p; else r[j] = r[j] + p;
            }
        }
        zzs[lane] = ((r[0] + r[1]) + (r[2] + r[3]))
                  + ((r[4] + r[5]) + (r[6] + r[7]));
    }
    __syncthreads();

    // ---- 4) argmin: lane = code, z broadcast from LDS ----
    float bestv[4]; int besti[4];            // running best per 16-px chunk
    #pragma unroll
    for (int c2 = 0; c2 < 4; ++c2) { bestv[c2] = FLT_MAX; besti[c2] = 0; }
    float* mybuf = sbuf[wave];
    const int spx = lane & 15;               // scan: my pixel within chunk
    const int sq  = lane >> 4;               // scan: my 16-code quarter
    const int kwbase = wave * 128;

    for (int t = 0; t < 2; ++t) {            // two 64-code tiles
        const int kb = kwbase + t * 64;
        // stage my code row into registers (per-lane contiguous dwordx4)
        float er[DIM];
        {
            const float4* rp = (const float4*)(cb + (size_t)(kb + lane) * DIM);
            #pragma unroll
            for (int j = 0; j < 16; ++j) ((float4*)er)[j] = rp[j];
        }
        const float ee = esq[kb + lane];     // my code's norm

        #pragma unroll
        for (int ch = 0; ch < 4; ++ch) {     // 4 chunks of 16 pixels
            for (int pg = 0; pg < 8; ++pg) { // 2 pixels per group
                const int p0 = ch * 16 + pg * 2;
                const int p1 = p0 + 1;
                const int sw0 = p0 & 15;
                const int sw1 = p1 & 15;
                float d0 = 0.f, d1 = 0.f;
                #pragma unroll
                for (int tt = 0; tt < 16; ++tt) {   // ascending c, single chain
                    const float4 v0 = vzT[p0 * 16 + (tt ^ sw0)];  // uniform bc
                    const float4 v1 = vzT[p1 * 16 + (tt ^ sw1)];  // uniform bc
                    d0 = __builtin_fmaf(er[4 * tt + 0], v0.x, d0);
                    d0 = __builtin_fmaf(er[4 * tt + 1], v0.y, d0);
                    d0 = __builtin_fmaf(er[4 * tt + 2], v0.z, d0);
                    d0 = __builtin_fmaf(er[4 * tt + 3], v0.w, d0);
                    d1 = __builtin_fmaf(er[4 * tt + 0], v1.x, d1);
                    d1 = __builtin_fmaf(er[4 * tt + 1], v1.y, d1);
                    d1 = __builtin_fmaf(er[4 * tt + 2], v1.z, d1);
                    d1 = __builtin_fmaf(er[4 * tt + 3], v1.w, d1);
                }
                float s0, s1;
                {
                    #pragma clang fp contract(off)
                    const float a0 = zzs[p0] + ee;
                    const float a1 = zzs[p1] + ee;
                    s0 = a0 - 2.0f * d0;
                    s1 = a1 - 2.0f * d1;
                }
                // park scores: [code=lane][pxr], pad-17 (17 coprime 32:
                // lane-stride-17 writes and code-stride-17 reads both 2-way)
                mybuf[lane * 17 + pg * 2]     = s0;
                mybuf[lane * 17 + pg * 2 + 1] = s1;
            }
            // scan chunk: lane owns pixel spx, codes [kb+sq*16, +16) asc.
            // Same-wave ds_write->ds_read: DS pipe processes a wave's LDS
            // ops in order; compiler keeps order (may-alias same array).
            float lv = FLT_MAX; int li = 0;
            #pragma unroll
            for (int j = 0; j < 16; ++j) {
                const float sc = mybuf[(sq * 16 + j) * 17 + spx];
                if (sc < lv) { lv = sc; li = kb + sq * 16 + j; }  // first-min
            }
            // merge 4 quarters, lex-(v, idx): lowest idx wins ties
            {
                const float ov = __shfl_xor(lv, 16, 64);
                const int   oi = __shfl_xor(li, 16, 64);
                if (ov < lv || (ov == lv && oi < li)) { lv = ov; li = oi; }
            }
            {
                const float ov = __shfl_xor(lv, 32, 64);
                const int   oi = __shfl_xor(li, 32, 64);
                if (ov < lv || (ov == lv && oi < li)) { lv = ov; li = oi; }
            }
            // tile merge: strict < keeps earlier tile (lower k) on ties
            if (lv < bestv[ch]) { bestv[ch] = lv; besti[ch] = li; }
        }
    }
    if (lane < 16) {
        #pragma unroll
        for (int ch = 0; ch < 4; ++ch) {
            cand_val[wave * 64 + ch * 16 + lane] = bestv[ch];
            cand_idx[wave * 64 + ch * 16 + lane] = besti[ch];
        }
    }
    __syncthreads();

    // ---- 5) reduce 8 wave-candidates per pixel; write indices output ----
    if (tid < 64) {
        float bv = cand_val[tid];
        int   bi = cand_idx[tid];
        #pragma unroll
        for (int w = 1; w < 8; ++w) {
            float v = cand_val[w * 64 + tid];
            int   i = cand_idx[w * 64 + tid];
            if (v < bv || (v == bv && i < bi)) { bv = v; bi = i; }
        }
        fidx[tid] = bi;
        out[IDX_OFF + n0 + tid] = (float)bi;
    }
    __syncthreads();

    // ---- 6) z_q write (coalesced by hw) + loss partial ----
    // 512 threads: px = lane, wave cg handles channels cg*8 .. cg*8+7
    const int px = tid & 63;
    const int cg = tid >> 6;      // 0..7
    const int mi = fidx[px];
    float lacc = 0.f;
    #pragma unroll
    for (int i = 0; i < 8; ++i) {
        const int c = cg * 8 + i;
        float q  = cb[mi * DIM + c];                    // L2-resident gather
        size_t go = zbase + (size_t)c * 1024 + px;
        float zv = z[go];                               // coalesced, L1-hot
        float d  = q - zv;
        lacc = __builtin_fmaf(d, d, lacc);
        out[go] = q;                                    // coalesced
    }
    #pragma unroll
    for (int off = 32; off > 0; off >>= 1)
        lacc += __shfl_down(lacc, off, 64);
    if (lane == 0) lred[wave] = lacc;
    __syncthreads();
    if (tid == 0) {
        float t = 0.f;
        #pragma unroll
        for (int w = 0; w < 8; ++w) t += lred[w];
        ws_partial[blockIdx.x] = t;
    }
}

// single block, 512 threads: sum the 512 block partials -> loss
__global__ __launch_bounds__(512)
void vq_loss_finalize(const float* __restrict__ ws_partial, float* __restrict__ out) {
    __shared__ float red[8];
    const int tid = threadIdx.x;
    float v = ws_partial[tid];
    #pragma unroll
    for (int off = 32; off > 0; off >>= 1)
        v += __shfl_down(v, off, 64);
    const int lane = tid & 63, wave = tid >> 6;
    if (lane == 0) red[wave] = v;
    __syncthreads();
    if (tid == 0) {
        float t = 0.f;
        #pragma unroll
        for (int w = 0; w < 8; ++w) t += red[w];
        out[LOSS_OFF] = t * LOSS_SCALE;
    }
}

extern "C" void kernel_launch(void* const* d_in, const int* in_sizes, int n_in,
                              void* d_out, int out_size, void* d_ws, size_t ws_size,
                              hipStream_t stream) {
    const float* z  = (const float*)d_in[0];   // 2097152 f32
    const float* cb = (const float*)d_in[1];   // 65536 f32
    float* out = (float*)d_out;
    float* ws  = (float*)d_ws;                 // needs 512 * 4 B

    vq_main<<<512, 512, 0, stream>>>(z, cb, out, ws);
    vq_loss_finalize<<<1, 512, 0, stream>>>(ws, out);
}

// Round 6
// 244.470 us; speedup vs baseline: 4.1265x; 4.1265x over previous
//
#include <hip/hip_runtime.h>
#include <float.h>

// VQ-VAE vector quantizer, MI355X fp32 vector-ALU version, round 7.
// z: [32,64,32,32] f32, codebook: [1024,64] f32
// out (f32 flat): z_q [2097152] | loss [1] | indices-as-float [32768]
//
// Numerics contract (DO NOT CHANGE — bitwise-matches the numpy fp32 ref):
//  - code/pixel norms: numpy pairwise-sum tree over 64 rounded squares,
//    fp contract OFF
//  - dot: single k-ordered fma chain per (pixel, code)
//  - score: fl(fl(zz+ee) - 2*dot), strict-< first-min, ascending k,
//    wave w owns codes [w*64, w*64+64), ascending-wave lex-(v,i) merge
//
// Round-7 perf change: rounds 4-6 all lost to the register allocator
// (any per-lane array >=64 floats spills or remats; r6's float4-punned
// er[] store defeated SROA -> 3 GB scratch traffic). Round-0's inner loop
// is the ONE loop proven to allocate cleanly (VGPR=76, zero excess HBM
// traffic) — its real limiter was the GRID: 256 blocks x 8 waves on 256
// CUs = 1 block/CU = 2 waves/SIMD, so s_load latency had nothing to hide
// behind (VALUBusy 44%). This round keeps that inner loop byte-for-byte
// and widens the block to 1024 threads = 16 waves (64-code slice per
// wave): 16 waves/CU = 4 waves/SIMD — exactly the cap VGPR=76 allows.

#define DIM       64
#define N_EMB     1024
#define LOSS_OFF  2097152
#define IDX_OFF   2097153
// loss = 1.25 * sum / 2^21  (exact fp32 constant)
#define LOSS_SCALE 5.9604644775390625e-07f

// numpy pairwise_sum over 64 elements of a^2, exact tree.
__device__ __forceinline__ float np_sumsq64(const float* a) {
    #pragma clang fp contract(off)
    float r[8];
    #pragma unroll
    for (int j = 0; j < 8; ++j) {
        float s = a[j] * a[j];
        #pragma unroll
        for (int m = 1; m < 8; ++m) {
            float p = a[j + 8 * m] * a[j + 8 * m];
            s = s + p;
        }
        r[j] = s;
    }
    return ((r[0] + r[1]) + (r[2] + r[3])) + ((r[4] + r[5]) + (r[6] + r[7]));
}

// grid 256 blocks x 1024 threads; block = 128 pixels (2/lane),
// 16 waves x 64-code slices
__global__ __launch_bounds__(1024, 4)
void vq_main(const float* __restrict__ z, const float* __restrict__ cb,
             float* __restrict__ out, float* __restrict__ ws_partial) {
    __shared__ float esq[N_EMB];          // 4 KB
    __shared__ float cand_val[16 * 128];  // 8 KB
    __shared__ int   cand_idx[16 * 128];  // 8 KB
    __shared__ int   fidx[128];
    __shared__ float lred[16];

    const int tid  = threadIdx.x;
    const int lane = tid & 63;
    const int wave = __builtin_amdgcn_readfirstlane(tid >> 6);  // uniform
    const int n0   = blockIdx.x * 128;         // first pixel of this block
    const int b    = n0 >> 10;                 // batch image (1024 px each)
    const int hw0  = n0 & 1023;
    const size_t zbase = (size_t)b * 65536 + (size_t)hw0;  // z[b][c][hw]

    // ---- 1) codebook squared norms -> LDS, numpy tree (1 code/thread) ----
    {
        #pragma clang fp contract(off)
        const int k = tid;
        float a[DIM];
        const float4* row = (const float4*)(cb + (size_t)k * DIM);
        #pragma unroll
        for (int j = 0; j < 16; ++j) ((float4*)a)[j] = row[j];
        esq[k] = np_sumsq64(a);
    }

    // ---- 2) two pixel vectors per lane (px0=lane, px1=lane+64) ----
    float vz0[DIM], vz1[DIM];
    #pragma unroll
    for (int c = 0; c < DIM; ++c) {
        vz0[c] = z[zbase + (size_t)c * 1024 + lane];        // coalesced
        vz1[c] = z[zbase + (size_t)c * 1024 + lane + 64];   // coalesced
    }
    const float zz0 = np_sumsq64(vz0);
    const float zz1 = np_sumsq64(vz1);

    __syncthreads();

    // ---- 3) argmin over this wave's 64-code slice, 4 fma chains ----
    float best0 = FLT_MAX, best1 = FLT_MAX;
    int   bidx0 = 0,       bidx1 = 0;
    const int kbase = wave * 64;
    for (int k = kbase; k < kbase + 64; k += 2) {   // uniform k -> s_load rows
        const float* e0 = cb + (size_t)k * DIM;
        const float* e1 = e0 + DIM;
        float d00 = 0.f, d01 = 0.f, d10 = 0.f, d11 = 0.f;
        #pragma unroll
        for (int c = 0; c < DIM; ++c) {
            const float a0 = e0[c];
            const float a1 = e1[c];
            d00 = __builtin_fmaf(a0, vz0[c], d00);   // code k,   px0
            d01 = __builtin_fmaf(a0, vz1[c], d01);   // code k,   px1
            d10 = __builtin_fmaf(a1, vz0[c], d10);   // code k+1, px0
            d11 = __builtin_fmaf(a1, vz1[c], d11);   // code k+1, px1
        }
        float s00, s01, s10, s11;
        {
            #pragma clang fp contract(off)
            const float p0 = zz0 + esq[k];
            const float p1 = zz1 + esq[k];
            const float q0 = zz0 + esq[k + 1];
            const float q1 = zz1 + esq[k + 1];
            s00 = p0 - 2.0f * d00;
            s01 = p1 - 2.0f * d01;
            s10 = q0 - 2.0f * d10;
            s11 = q1 - 2.0f * d11;
        }
        if (s00 < best0) { best0 = s00; bidx0 = k; }      // ascending k =>
        if (s10 < best0) { best0 = s10; bidx0 = k + 1; }  // first-min kept
        if (s01 < best1) { best1 = s01; bidx1 = k; }
        if (s11 < best1) { best1 = s11; bidx1 = k + 1; }
    }
    cand_val[wave * 128 + lane]      = best0;
    cand_idx[wave * 128 + lane]      = bidx0;
    cand_val[wave * 128 + 64 + lane] = best1;
    cand_idx[wave * 128 + 64 + lane] = bidx1;
    __syncthreads();

    // ---- 4) reduce 16 wave-candidates per pixel; write indices output ----
    // ascending wave = ascending code range; lex-(v,i) keeps first-min.
    if (tid < 128) {
        float bv = cand_val[tid];
        int   bi = cand_idx[tid];
        #pragma unroll
        for (int w = 1; w < 16; ++w) {
            float v = cand_val[w * 128 + tid];
            int   i = cand_idx[w * 128 + tid];
            if (v < bv || (v == bv && i < bi)) { bv = v; bi = i; }
        }
        fidx[tid] = bi;
        out[IDX_OFF + n0 + tid] = (float)bi;
    }
    __syncthreads();

    // ---- 5) z_q write (coalesced by hw) + loss partial ----
    // 1024 threads: px = tid&127, wave-group cg handles channels cg*8..+7
    const int px = tid & 127;
    const int cg = tid >> 7;      // 0..7
    const int mi = fidx[px];
    float lacc = 0.f;
    #pragma unroll
    for (int i = 0; i < 8; ++i) {
        const int c = cg * 8 + i;
        float q  = cb[mi * DIM + c];                    // L2-resident gather
        size_t go = zbase + (size_t)c * 1024 + px;
        float zv = z[go];                               // coalesced
        float d  = q - zv;
        lacc = __builtin_fmaf(d, d, lacc);
        out[go] = q;                                    // coalesced
    }
    #pragma unroll
    for (int off = 32; off > 0; off >>= 1)
        lacc += __shfl_down(lacc, off, 64);
    if (lane == 0) lred[wave] = lacc;
    __syncthreads();
    if (tid == 0) {
        float t = 0.f;
        #pragma unroll
        for (int w = 0; w < 16; ++w) t += lred[w];
        ws_partial[blockIdx.x] = t;
    }
}

// single block, 256 threads: sum the 256 block partials -> loss
__global__ __launch_bounds__(256)
void vq_loss_finalize(const float* __restrict__ ws_partial, float* __restrict__ out) {
    __shared__ float red[4];
    const int tid = threadIdx.x;
    float v = ws_partial[tid];
    #pragma unroll
    for (int off = 32; off > 0; off >>= 1)
        v += __shfl_down(v, off, 64);
    const int lane = tid & 63, wave = tid >> 6;
    if (lane == 0) red[wave] = v;
    __syncthreads();
    if (tid == 0) {
        float t = 0.f;
        #pragma unroll
        for (int w = 0; w < 4; ++w) t += red[w];
        out[LOSS_OFF] = t * LOSS_SCALE;
    }
}

extern "C" void kernel_launch(void* const* d_in, const int* in_sizes, int n_in,
                              void* d_out, int out_size, void* d_ws, size_t ws_size,
                              hipStream_t stream) {
    const float* z  = (const float*)d_in[0];   // 2097152 f32
    const float* cb = (const float*)d_in[1];   // 65536 f32
    float* out = (float*)d_out;
    float* ws  = (float*)d_ws;                 // needs 256 * 4 B

    vq_main<<<256, 1024, 0, stream>>>(z, cb, out, ws);
    vq_loss_finalize<<<1, 256, 0, stream>>>(ws, out);
}

// Round 7
// 159.165 us; speedup vs baseline: 6.3381x; 1.5359x over previous
//
#include <hip/hip_runtime.h>
#include <float.h>

// VQ-VAE vector quantizer, MI355X fp32 vector-ALU version, round 8.
// z: [32,64,32,32] f32, codebook: [1024,64] f32
// out (f32 flat): z_q [2097152] | loss [1] | indices-as-float [32768]
//
// Numerics contract (DO NOT CHANGE — matches the fp32 ref's argmin exactly):
//  - code/pixel norms: numpy pairwise-sum tree over 64 rounded squares,
//    fp contract OFF (streamed 8-chunk form: r[j] = sum_m a[8m+j]^2
//    ascending m — identical element->partial grouping as the flat tree)
//  - dot: single c-ascending fma chain per (pixel, code)
//  - score: fl(fl(zz+ee) - 2*dot), strict-< first-min, ascending k,
//    wave w owns codes [w*128, w*128+128), ascending-wave lex-(v,i) merge
//
// Round-8 perf change — allocator ledger across 7 rounds:
//   cap 256 + 128 z floats/lane -> AGPR-parked (r0: VGPR=76, 44% busy)
//   cap 128 + 128 z floats/lane -> full scratch  (r7: 300 MB HBM excess)
//   cap 128 +  64 z floats/lane -> ~6-float spill (r4: the float4-punned
//     store into a[64] in stage 1 defeated SROA; r6's punned er[] = same bug)
// Rule: z floats/lane <= cap-30 AND no float4-punned stores into float
// arrays. This round: 1 px/lane (vz[64], scalar loads, SROA-clean),
// streamed norm trees (no second 64-array ever live), cap 128 via
// launch_bounds(512,4) -> 2 blocks/CU, 16 waves/CU = 4 waves/SIMD.
// K-loop / merge / epilogue identical to every passing round.

#define DIM       64
#define N_EMB     1024
#define LOSS_OFF  2097152
#define IDX_OFF   2097153
// loss = 1.25 * sum / 2^21  (exact fp32 constant)
#define LOSS_SCALE 5.9604644775390625e-07f

// grid 512 blocks x 512 threads; block = 64 pixels (1/lane),
// 8 waves x 128-code slices
__global__ __launch_bounds__(512, 4)
void vq_main(const float* __restrict__ z, const float* __restrict__ cb,
             float* __restrict__ out, float* __restrict__ ws_partial) {
    __shared__ float esq[N_EMB];       // 4 KB
    __shared__ float cand_val[8 * 64]; // 2 KB
    __shared__ int   cand_idx[8 * 64]; // 2 KB
    __shared__ int   fidx[64];
    __shared__ float lred[8];

    const int tid  = threadIdx.x;
    const int lane = tid & 63;
    const int wave = __builtin_amdgcn_readfirstlane(tid >> 6);  // uniform
    const int n0   = blockIdx.x * 64;          // first pixel of this block
    const int b    = n0 >> 10;                 // batch image (1024 px each)
    const int hw0  = n0 & 1023;
    const size_t zbase = (size_t)b * 65536 + (size_t)hw0;  // z[b][c][hw]

    // ---- 1) codebook squared norms -> LDS (2 codes/thread), streamed ----
    // float4 locals -> scalars only; no stores into a float array (SROA-safe).
    {
        #pragma clang fp contract(off)
        for (int t = 0; t < 2; ++t) {
            const int k = tid * 2 + t;
            const float4* row = (const float4*)(cb + (size_t)k * DIM);
            float r[8];
            #pragma unroll
            for (int m = 0; m < 8; ++m) {
                const float4 x0 = row[2 * m];
                const float4 x1 = row[2 * m + 1];
                const float a0 = x0.x, a1 = x0.y, a2 = x0.z, a3 = x0.w;
                const float a4 = x1.x, a5 = x1.y, a6 = x1.z, a7 = x1.w;
                if (m == 0) {
                    r[0] = a0 * a0; r[1] = a1 * a1; r[2] = a2 * a2; r[3] = a3 * a3;
                    r[4] = a4 * a4; r[5] = a5 * a5; r[6] = a6 * a6; r[7] = a7 * a7;
                } else {
                    r[0] = r[0] + a0 * a0; r[1] = r[1] + a1 * a1;
                    r[2] = r[2] + a2 * a2; r[3] = r[3] + a3 * a3;
                    r[4] = r[4] + a4 * a4; r[5] = r[5] + a5 * a5;
                    r[6] = r[6] + a6 * a6; r[7] = r[7] + a7 * a7;
                }
            }
            esq[k] = ((r[0] + r[1]) + (r[2] + r[3]))
                   + ((r[4] + r[5]) + (r[6] + r[7]));
        }
    }

    // ---- 2) one pixel vector per lane + streamed zz (same numpy tree) ----
    float vz[DIM];
    float zz;
    {
        #pragma clang fp contract(off)
        float r[8];
        #pragma unroll
        for (int m = 0; m < 8; ++m) {
            #pragma unroll
            for (int j = 0; j < 8; ++j)
                vz[8 * m + j] = z[zbase + (size_t)(8 * m + j) * 1024 + lane];
            #pragma unroll
            for (int j = 0; j < 8; ++j) {
                const float p = vz[8 * m + j] * vz[8 * m + j];
                if (m == 0) r[j] = p; else r[j] = r[j] + p;
            }
        }
        zz = ((r[0] + r[1]) + (r[2] + r[3]))
           + ((r[4] + r[5]) + (r[6] + r[7]));
    }

    __syncthreads();

    // ---- 3) argmin over this wave's 128-code slice, 2 fma chains ----
    float best = FLT_MAX;
    int   bidx = 0;
    const int kbase = wave * 128;
    for (int k = kbase; k < kbase + 128; k += 2) {   // uniform k -> s_load rows
        const float* e0 = cb + (size_t)k * DIM;
        const float* e1 = e0 + DIM;
        float d0 = 0.f, d1 = 0.f;
        #pragma unroll
        for (int c = 0; c < DIM; ++c) {
            d0 = __builtin_fmaf(e0[c], vz[c], d0);   // code k
            d1 = __builtin_fmaf(e1[c], vz[c], d1);   // code k+1
        }
        float s0, s1;
        {
            #pragma clang fp contract(off)
            const float p0 = zz + esq[k];
            const float p1 = zz + esq[k + 1];
            s0 = p0 - 2.0f * d0;
            s1 = p1 - 2.0f * d1;
        }
        if (s0 < best) { best = s0; bidx = k; }      // ascending k =>
        if (s1 < best) { best = s1; bidx = k + 1; }  // first-min kept
    }
    cand_val[wave * 64 + lane] = best;
    cand_idx[wave * 64 + lane] = bidx;
    __syncthreads();

    // ---- 4) reduce 8 wave-candidates per pixel; write indices output ----
    if (tid < 64) {
        float bv = cand_val[tid];
        int   bi = cand_idx[tid];
        #pragma unroll
        for (int w = 1; w < 8; ++w) {
            float v = cand_val[w * 64 + tid];
            int   i = cand_idx[w * 64 + tid];
            if (v < bv || (v == bv && i < bi)) { bv = v; bi = i; }
        }
        fidx[tid] = bi;
        out[IDX_OFF + n0 + tid] = (float)bi;
    }
    __syncthreads();

    // ---- 5) z_q write (coalesced by hw) + loss partial ----
    // 512 threads: px = lane, wave cg handles channels cg*8 .. cg*8+7
    const int px = tid & 63;
    const int cg = tid >> 6;      // 0..7
    const int mi = fidx[px];
    float lacc = 0.f;
    #pragma unroll
    for (int i = 0; i < 8; ++i) {
        const int c = cg * 8 + i;
        float q  = cb[mi * DIM + c];                    // L2-resident gather
        size_t go = zbase + (size_t)c * 1024 + px;
        float zv = z[go];                               // coalesced, L1-hot
        float d  = q - zv;
        lacc = __builtin_fmaf(d, d, lacc);
        out[go] = q;                                    // coalesced
    }
    #pragma unroll
    for (int off = 32; off > 0; off >>= 1)
        lacc += __shfl_down(lacc, off, 64);
    if (lane == 0) lred[wave] = lacc;
    __syncthreads();
    if (tid == 0) {
        float t = 0.f;
        #pragma unroll
        for (int w = 0; w < 8; ++w) t += lred[w];
        ws_partial[blockIdx.x] = t;
    }
}

// single block, 512 threads: sum the 512 block partials -> loss
__global__ __launch_bounds__(512)
void vq_loss_finalize(const float* __restrict__ ws_partial, float* __restrict__ out) {
    __shared__ float red[8];
    const int tid = threadIdx.x;
    float v = ws_partial[tid];
    #pragma unroll
    for (int off = 32; off > 0; off >>= 1)
        v += __shfl_down(v, off, 64);
    const int lane = tid & 63, wave = tid >> 6;
    if (lane == 0) red[wave] = v;
    __syncthreads();
    if (tid == 0) {
        float t = 0.f;
        #pragma unroll
        for (int w = 0; w < 8; ++w) t += red[w];
        out[LOSS_OFF] = t * LOSS_SCALE;
    }
}

extern "C" void kernel_launch(void* const* d_in, const int* in_sizes, int n_in,
                              void* d_out, int out_size, void* d_ws, size_t ws_size,
                              hipStream_t stream) {
    const float* z  = (const float*)d_in[0];   // 2097152 f32
    const float* cb = (const float*)d_in[1];   // 65536 f32
    float* out = (float*)d_out;
    float* ws  = (float*)d_ws;                 // needs 512 * 4 B

    vq_main<<<512, 512, 0, stream>>>(z, cb, out, ws);
    vq_loss_finalize<<<1, 512, 0, stream>>>(ws, out);
}